// Round 1
// baseline (163.707 us; speedup 1.0000x reference)
//
#include <hip/hip_runtime.h>

typedef unsigned int uint;
typedef unsigned short ushort;
typedef __attribute__((ext_vector_type(8))) short bf16x8;
typedef __attribute__((ext_vector_type(4))) float f32x4;

namespace {
constexpr int kS = 2048;
constexpr int kD = 512;
constexpr int kH = 8;
constexpr int kBand = 16;

template <bool C, typename A, typename B> struct cond { using type = A; };
template <typename A, typename B> struct cond<false, A, B> { using type = B; };
}  // namespace

static __device__ __forceinline__ ushort f2bf(float f) {
  uint u = __builtin_bit_cast(uint, f);
  u = (u + 0x7fffu + ((u >> 16) & 1u)) >> 16;  // RNE
  return (ushort)u;
}

// 8 fp32 -> bf16x8 via v_cvt_pk_bf16_f32 (RNE; bit-identical to f2bf).
static __device__ __forceinline__ bf16x8 cvt8(f32x4 lo, f32x4 hi) {
  uint4 r;
  asm("v_cvt_pk_bf16_f32 %0, %1, %2" : "=v"(r.x) : "v"(lo[0]), "v"(lo[1]));
  asm("v_cvt_pk_bf16_f32 %0, %1, %2" : "=v"(r.y) : "v"(lo[2]), "v"(lo[3]));
  asm("v_cvt_pk_bf16_f32 %0, %1, %2" : "=v"(r.z) : "v"(hi[0]), "v"(hi[1]));
  asm("v_cvt_pk_bf16_f32 %0, %1, %2" : "=v"(r.w) : "v"(hi[2]), "v"(hi[3]));
  return __builtin_bit_cast(bf16x8, r);
}

// global -> LDS direct DMA, 16B/lane. LDS dest = wave-uniform base + lane*16.
#define GLD16(gp, lp)                                                   \
  __builtin_amdgcn_global_load_lds(                                     \
      (const __attribute__((address_space(1))) uint*)(gp),              \
      (__attribute__((address_space(3))) uint*)(lp), 16, 0, 0)

// ---------------------------------------------------------------------------
// Prep: weights only now (q/k/v conversion folded into the GEMM A-path).
// 256 blocks: WT[z][n][k] = bf16(W[z][k][n]).
// ---------------------------------------------------------------------------
__global__ __launch_bounds__(256) void prep_kernel(
    const float* __restrict__ wq, const float* __restrict__ wk,
    const float* __restrict__ wv, const float* __restrict__ wo,
    ushort* __restrict__ WT) {
  __shared__ float Ws[64][65];
  const int w = blockIdx.x;  // 0..255
  const int tid = threadIdx.x;
  const int z = w >> 6;
  const float* W = z == 0 ? wq : (z == 1 ? wk : (z == 2 ? wv : wo));
  ushort* T = WT + (size_t)z * kD * kD;
  const int kt = ((w >> 3) & 7) * 64, nt = (w & 7) * 64;
  const int r = tid >> 2, c0 = (tid & 3) * 16;
#pragma unroll
  for (int i = 0; i < 4; ++i) {
    const float4 x =
        *(const float4*)(W + (size_t)(kt + r) * kD + nt + c0 + i * 4);
    Ws[r][c0 + i * 4 + 0] = x.x;
    Ws[r][c0 + i * 4 + 1] = x.y;
    Ws[r][c0 + i * 4 + 2] = x.z;
    Ws[r][c0 + i * 4 + 3] = x.w;
  }
  __syncthreads();
  const int n = tid >> 2, k0 = (tid & 3) * 16;
  alignas(16) ushort tmp[16];
#pragma unroll
  for (int i = 0; i < 16; ++i) tmp[i] = f2bf(Ws[k0 + i][n]);
  ushort* dst = T + (size_t)(nt + n) * kD + kt + k0;
  *(uint4*)(dst + 0) = *(const uint4*)&tmp[0];
  *(uint4*)(dst + 8) = *(const uint4*)&tmp[8];
}

// ---------------------------------------------------------------------------
// TM x 128 BK=32 bf16 MFMA GEMM, 3-stage global_load_lds pipeline, one raw
// s_barrier + vmcnt(loads-per-stage) per iter.
// AF32=true: A operand is fp32 (q/k/v read directly from HBM, no bf16
// pre-pass); fragments converted at ds_read time via v_cvt_pk_bf16_f32.
// A rows are then 32 f32 = 8 x 16B chunks; chunk c of row r holds global
// chunk c ^ (r&7) so the two b128 fragment reads stay 2-way-bank-free.
// AF32=false: A is bf16 rows of 32 = 4 chunks, s(r) = (r&3)^((r>>2)&3).
// XCD-aware swizzle: the 4 col-blocks of a row-block share an XCD (x%8) and
// a dispatch window, so the A tile is HBM-fetched once and L2-hit 3x.
// mode = mode_arg + blockIdx.z:
//   0: fp32 q @ WTq + bq -> Qp (bf16 [tok][512])
//   1: fp32 k @ WTk + bk -> Kp (bf16 [tok][512])
//   2: fp32 v @ WTv + bv -> VT (bf16 [bh*64+d][2048], transposed)
//   3: Ob(bf16) @ WTo + bo -> out (fp32 [tok][512])
// ---------------------------------------------------------------------------
template <int TM, bool AF32>
__global__ __launch_bounds__(256) void gemm_kernel(
    const float* __restrict__ qf, const float* __restrict__ kf,
    const float* __restrict__ vf, const ushort* __restrict__ obp,
    const ushort* __restrict__ WT, const float* __restrict__ bq,
    const float* __restrict__ bk, const float* __restrict__ bv,
    const float* __restrict__ bo, ushort* __restrict__ Qp,
    ushort* __restrict__ Kp, ushort* __restrict__ VT,
    float* __restrict__ outp, int mode_arg) {
  const int mode = mode_arg + blockIdx.z;
  const void* Abv;
  const float* bias;
  switch (mode) {
    case 0: Abv = qf; bias = bq; break;
    case 1: Abv = kf; bias = bk; break;
    case 2: Abv = vf; bias = bv; break;
    default: Abv = obp; bias = bo; break;
  }
  using AT = typename cond<AF32, float, ushort>::type;
  const AT* Abt = (const AT*)Abv;
  const ushort* BT = WT + (size_t)mode * kD * kD;

  // A stages: [st * A_STAGE]; B stages: [B_BASE + st*4096] (ushort units).
  constexpr int A_STAGE = TM * (AF32 ? 64 : 32);  // ushort units per stage
  constexpr int B_BASE = 3 * A_STAGE;
  constexpr int NI = (TM == 128) ? 4 : 2;
  constexpr int AI = AF32 ? TM / 32 : TM / 64;  // A DMA issues per stage
  __shared__ alignas(16) ushort smem[B_BASE + 12288];

  const int tid = threadIdx.x;
  const int wave = tid >> 6, lane = tid & 63, l15 = lane & 15, qd = lane >> 4;
  const int wm = (TM == 128) ? (wave >> 1) * 64 : 0;
  const int wn = (TM == 128) ? (wave & 1) * 64 : wave * 32;
  // XCD-aware swizzle: x%8 = XCD (round-robin dispatch). Same row-block's 4
  // col-blocks get x values 8 apart -> same XCD, consecutive window.
  const int lin = blockIdx.x;
  const int xcd = lin & 7, j = lin >> 3;
  const int rblk = xcd + 8 * (j >> 2), cblk = j & 3;
  const int row0 = rblk * TM, col0 = cblk * 128;
  const int sw = (l15 & 3) ^ (l15 >> 2);  // B swizzle (and bf16-A swizzle)

  const AT* pA[AI];
  const ushort* pB[2];
  uint ldsA[AI], ldsB[2];
#pragma unroll
  for (int i = 0; i < AI; ++i) {
    const int linear = i * 256 + tid;
    int r, g;
    if constexpr (AF32) {
      r = linear >> 3;             // 8 chunks of 4 floats per 32-f32 row
      g = (linear & 7) ^ (r & 7);  // pre-swizzled global chunk
    } else {
      r = linear >> 2;  // 4 chunks of 8 bf16 per 32-bf16 row
      g = (linear & 3) ^ ((r & 3) ^ ((r >> 2) & 3));
    }
    pA[i] = Abt + (size_t)(row0 + r) * kD + g * (AF32 ? 4 : 8);
    ldsA[i] = (uint)(i * 256 + wave * 64) * 8;
  }
#pragma unroll
  for (int i = 0; i < 2; ++i) {
    const int linear = i * 256 + tid;
    const int r = linear >> 2, c = linear & 3;
    const int g = c ^ ((r & 3) ^ ((r >> 2) & 3));
    pB[i] = BT + (size_t)(col0 + r) * kD + g * 8;
    ldsB[i] = (uint)B_BASE + (uint)(i * 256 + wave * 64) * 8;
  }

// kk is in A-elements per K-step (32 floats or 32 ushorts — same count).
#define ISSUE(kk, st)                                                     \
  {                                                                       \
    _Pragma("unroll") for (int i = 0; i < AI; ++i)                        \
        GLD16(pA[i] + (kk), &smem[ldsA[i] + (st) * A_STAGE]);             \
    _Pragma("unroll") for (int i = 0; i < 2; ++i)                         \
        GLD16(pB[i] + (kk), &smem[ldsB[i] + (st) * 4096]);                \
  }

  f32x4 acc[4][NI];
#pragma unroll
  for (int mi = 0; mi < 4; ++mi)
#pragma unroll
    for (int ni = 0; ni < NI; ++ni) acc[mi][ni] = (f32x4)(0.f);

  ISSUE(0, 0);
  ISSUE(32, 1);
#pragma unroll
  for (int it = 0; it < 16; ++it) {
    // vmcnt(N) = loads-in-flight for the NEXT stage only: one stage is
    // AI+2 per-thread loads. fp32-A TM=128 -> 6; bf16-A TM=64 -> 3.
    if (it < 15) {
      if constexpr (AI + 2 == 6) {
        asm volatile("s_waitcnt vmcnt(6) lgkmcnt(0)\n\ts_barrier" ::: "memory");
      } else {
        static_assert(AI + 2 == 3 || AI + 2 == 6, "unexpected stage size");
        asm volatile("s_waitcnt vmcnt(3) lgkmcnt(0)\n\ts_barrier" ::: "memory");
      }
    } else {
      asm volatile("s_waitcnt vmcnt(0) lgkmcnt(0)\n\ts_barrier" ::: "memory");
    }
    if (it < 14) ISSUE((it + 2) * 32, (it + 2) % 3);
    bf16x8 af[4], br[NI];
    if constexpr (AF32) {
      const float* as = (const float*)&smem[(it % 3) * A_STAGE];
#pragma unroll
      for (int mi = 0; mi < 4; ++mi) {
        const int row = wm + mi * 16 + l15;
        const int s2 = l15 & 7;  // == row & 7
        const f32x4 lo = *(const f32x4*)&as[row * 32 + ((2 * qd) ^ s2) * 4];
        const f32x4 hi = *(const f32x4*)&as[row * 32 + ((2 * qd + 1) ^ s2) * 4];
        af[mi] = cvt8(lo, hi);
      }
    } else {
      const ushort* as = &smem[(it % 3) * A_STAGE];
#pragma unroll
      for (int mi = 0; mi < 4; ++mi)
        af[mi] = *(const bf16x8*)&as[(wm + mi * 16 + l15) * 32 + (qd ^ sw) * 8];
    }
    const ushort* bs = &smem[B_BASE + (it % 3) * 4096];
#pragma unroll
    for (int ni = 0; ni < NI; ++ni)
      br[ni] = *(const bf16x8*)&bs[(wn + ni * 16 + l15) * 32 + (qd ^ sw) * 8];
#pragma unroll
    for (int mi = 0; mi < 4; ++mi)
#pragma unroll
      for (int ni = 0; ni < NI; ++ni)
        acc[mi][ni] = __builtin_amdgcn_mfma_f32_16x16x32_bf16(
            af[mi], br[ni], acc[mi][ni], 0, 0, 0);
  }
#undef ISSUE

  float bcol[NI];
#pragma unroll
  for (int ni = 0; ni < NI; ++ni) bcol[ni] = bias[col0 + wn + ni * 16 + l15];

  if (mode == 3) {  // fp32 direct stores
#pragma unroll
    for (int mi = 0; mi < 4; ++mi)
#pragma unroll
      for (int ni = 0; ni < NI; ++ni) {
        const int n_g = col0 + wn + ni * 16 + l15;
#pragma unroll
        for (int r = 0; r < 4; ++r) {
          const int token = row0 + wm + mi * 16 + qd * 4 + r;
          outp[(size_t)token * kD + n_g] = acc[mi][ni][r] + bcol[ni];
        }
      }
    return;
  }

  __syncthreads();  // safe to reuse smem for the epilogue transpose

  // bf16 outputs: per-wave 64x64 transpose through LDS (stride 72 ushorts),
  // then 8 x dwordx4 global stores per lane.
  ushort* T = &smem[wave * 4608];
  if (mode <= 1) {  // place [token_local][d_local]
#pragma unroll
    for (int mi = 0; mi < 4; ++mi)
#pragma unroll
      for (int ni = 0; ni < NI; ++ni)
#pragma unroll
        for (int r = 0; r < 4; ++r)
          T[(mi * 16 + qd * 4 + r) * 72 + ni * 16 + l15] =
              f2bf(acc[mi][ni][r] + bcol[ni]);
  } else {  // mode 2: place [d_local][token_local]
#pragma unroll
    for (int mi = 0; mi < 4; ++mi)
#pragma unroll
      for (int ni = 0; ni < NI; ++ni)
#pragma unroll
        for (int r = 0; r < 4; ++r)
          T[(ni * 16 + l15) * 72 + mi * 16 + qd * 4 + r] =
              f2bf(acc[mi][ni][r] + bcol[ni]);
  }
  asm volatile("s_waitcnt lgkmcnt(0)" ::: "memory");  // wave-local visibility

  const ushort* Trow = &smem[wave * 4608 + lane * 72];
  if (mode <= 1) {
    ushort* C = (mode == 0) ? Qp : Kp;
    ushort* dst = C + (size_t)(row0 + wm + lane) * kD + col0 + wn;
#pragma unroll
    for (int c = 0; c < 8; ++c)
      *(uint4*)(dst + c * 8) = *(const uint4*)(Trow + c * 8);
  } else {
    const int n_g = col0 + wn + lane;
    const int h = n_g >> 6, d = n_g & 63;
    const int t0 = row0 + wm;
    const int b = t0 >> 11, ss = t0 & (kS - 1);
    ushort* dst = VT + ((size_t)(b * kH + h) * 64 + d) * kS + ss;
#pragma unroll
    for (int c = 0; c < 8; ++c)
      *(uint4*)(dst + c * 8) = *(const uint4*)(Trow + c * 8);
  }
}

// ---------------------------------------------------------------------------
// MFMA banded attention. One wave per 64-query tile per (b,h). grid (32,32).
// ---------------------------------------------------------------------------
__global__ __launch_bounds__(64, 1) void attn_kernel(
    const ushort* __restrict__ Qp, const ushort* __restrict__ Kp,
    const ushort* __restrict__ VT, ushort* __restrict__ Ob) {
  __shared__ alignas(16) ushort Pl[64 * 104];  // P scatter; reused for O xpose

  const int lane = threadIdx.x, l15 = lane & 15, qd = lane >> 4;
  const int bh = blockIdx.y, b = bh >> 3, h = bh & 7;
  const int q0 = blockIdx.x * 64;
  const int colA = h * 64;

  bf16x8 qf[4][2], kf[6][2];
#pragma unroll
  for (int mi = 0; mi < 4; ++mi) {
    const size_t base =
        ((size_t)b * kS + q0 + mi * 16 + l15) * kD + colA + qd * 8;
#pragma unroll
    for (int kc = 0; kc < 2; ++kc)
      qf[mi][kc] = *(const bf16x8*)&Qp[base + kc * 32];
  }
#pragma unroll
  for (int ni = 0; ni < 6; ++ni) {
    int key = q0 - kBand + ni * 16 + l15;
    key = key < 0 ? 0 : (key > kS - 1 ? kS - 1 : key);  // clamp; masked below
    const size_t base = ((size_t)b * kS + key) * kD + colA + qd * 8;
#pragma unroll
    for (int kc = 0; kc < 2; ++kc)
      kf[ni][kc] = *(const bf16x8*)&Kp[base + kc * 32];
  }

  f32x4 S[4][6];
#pragma unroll
  for (int mi = 0; mi < 4; ++mi)
#pragma unroll
    for (int ni = 0; ni < 6; ++ni) S[mi][ni] = (f32x4)(0.f);
#pragma unroll
  for (int mi = 0; mi < 4; ++mi)
#pragma unroll
    for (int ni = 0; ni < 6; ++ni)
#pragma unroll
      for (int kc = 0; kc < 2; ++kc)
        S[mi][ni] = __builtin_amdgcn_mfma_f32_16x16x32_bf16(
            qf[mi][kc], kf[ni][kc], S[mi][ni], 0, 0, 0);

#pragma unroll
  for (int mi = 0; mi < 4; ++mi)
#pragma unroll
    for (int ni = 0; ni < 6; ++ni)
#pragma unroll
      for (int r = 0; r < 4; ++r) {
        const int q_local = mi * 16 + qd * 4 + r;
        const int key_local = ni * 16 + l15;
        const int key = q0 - kBand + key_local;
        const int dlt = key_local - q_local;
        const bool ok = (dlt >= 0) && (dlt <= 32) && (key >= 0) && (key < kS);
        S[mi][ni][r] = ok ? S[mi][ni][r] * 0.125f : -3.0e38f;
      }

  float inv[4][4];
#pragma unroll
  for (int mi = 0; mi < 4; ++mi)
#pragma unroll
    for (int r = 0; r < 4; ++r) {
      float m = S[mi][0][r];
#pragma unroll
      for (int ni = 1; ni < 6; ++ni) m = fmaxf(m, S[mi][ni][r]);
      m = fmaxf(m, __shfl_xor(m, 1));
      m = fmaxf(m, __shfl_xor(m, 2));
      m = fmaxf(m, __shfl_xor(m, 4));
      m = fmaxf(m, __shfl_xor(m, 8));
      float s = 0.f;
#pragma unroll
      for (int ni = 0; ni < 6; ++ni) {
        const float e = __expf(S[mi][ni][r] - m);
        S[mi][ni][r] = e;
        s += e;
      }
      s += __shfl_xor(s, 1);
      s += __shfl_xor(s, 2);
      s += __shfl_xor(s, 4);
      s += __shfl_xor(s, 8);
      inv[mi][r] = 1.f / s;
    }

  // P -> LDS (C-layout scatter, stride 104), read back in A-layout
#pragma unroll
  for (int mi = 0; mi < 4; ++mi)
#pragma unroll
    for (int ni = 0; ni < 6; ++ni)
#pragma unroll
      for (int r = 0; r < 4; ++r)
        Pl[(mi * 16 + qd * 4 + r) * 104 + ni * 16 + l15] = f2bf(S[mi][ni][r]);
  __syncthreads();

  f32x4 O[4][4];
#pragma unroll
  for (int mi = 0; mi < 4; ++mi)
#pragma unroll
    for (int nt = 0; nt < 4; ++nt) O[mi][nt] = (f32x4)(0.f);

#pragma unroll
  for (int kc = 0; kc < 3; ++kc) {
    bf16x8 pf[4], vfr[4];
#pragma unroll
    for (int mi = 0; mi < 4; ++mi)
      pf[mi] = *(const bf16x8*)&Pl[(mi * 16 + l15) * 104 + kc * 32 + qd * 8];
    int kb0 = q0 - kBand + kc * 32 + qd * 8;
    kb0 = kb0 < 0 ? 0 : (kb0 > kS - 8 ? kS - 8 : kb0);  // clamp; P=0 there
#pragma unroll
    for (int nt = 0; nt < 4; ++nt)
      vfr[nt] =
          *(const bf16x8*)&VT[((size_t)bh * 64 + nt * 16 + l15) * kS + kb0];
#pragma unroll
    for (int mi = 0; mi < 4; ++mi)
#pragma unroll
      for (int nt = 0; nt < 4; ++nt)
        O[mi][nt] = __builtin_amdgcn_mfma_f32_16x16x32_bf16(pf[mi], vfr[nt],
                                                            O[mi][nt], 0, 0, 0);
  }

  // O transpose through LDS (reuse Pl, stride 72), 8 x dwordx4 stores/lane
#pragma unroll
  for (int mi = 0; mi < 4; ++mi)
#pragma unroll
    for (int nt = 0; nt < 4; ++nt)
#pragma unroll
      for (int r = 0; r < 4; ++r)
        Pl[(mi * 16 + qd * 4 + r) * 72 + nt * 16 + l15] =
            f2bf(O[mi][nt][r] * inv[mi][r]);
  asm volatile("s_waitcnt lgkmcnt(0)" ::: "memory");

  ushort* dst = Ob + ((size_t)b * kS + q0 + lane) * kD + colA;
  const ushort* Trow = &Pl[lane * 72];
#pragma unroll
  for (int c = 0; c < 8; ++c)
    *(uint4*)(dst + c * 8) = *(const uint4*)(Trow + c * 8);
}

extern "C" void kernel_launch(void* const* d_in, const int* in_sizes, int n_in,
                              void* d_out, int out_size, void* d_ws,
                              size_t ws_size, hipStream_t stream) {
  const float* q = (const float*)d_in[0];
  const float* k = (const float*)d_in[1];
  const float* v = (const float*)d_in[2];
  const float* wq = (const float*)d_in[3];
  const float* bq = (const float*)d_in[4];
  const float* wk = (const float*)d_in[5];
  const float* bk = (const float*)d_in[6];
  const float* wv = (const float*)d_in[7];
  const float* bv = (const float*)d_in[8];
  const float* wo = (const float*)d_in[9];
  const float* bo = (const float*)d_in[10];
  float* out = (float*)d_out;

  // ws (~34 MB), no aliasing. qb/kb/vb eliminated (fp32-A GEMM).
  const size_t n1 = (size_t)8192 * kD;  // 4M ushorts = 8 MB
  ushort* Qp = (ushort*)d_ws;
  ushort* Kp = Qp + n1;
  ushort* VT = Kp + n1;
  ushort* Ob = VT + n1;
  ushort* WT = Ob + n1;

  prep_kernel<<<dim3(256), 256, 0, stream>>>(wq, wk, wv, wo, WT);
  gemm_kernel<128, true><<<dim3(256, 1, 3), 256, 0, stream>>>(  // modes 0,1,2
      q, k, v, Ob, WT, bq, bk, bv, bo, Qp, Kp, VT, out, 0);
  attn_kernel<<<dim3(kS / 64, 32), 64, 0, stream>>>(Qp, Kp, VT, Ob);
  gemm_kernel<64, false><<<dim3(512, 1, 1), 256, 0, stream>>>(  // mode 3
      q, k, v, Ob, WT, bq, bk, bv, bo, Qp, Kp, VT, out, 3);
}

// Round 2
// 161.623 us; speedup vs baseline: 1.0129x; 1.0129x over previous
//
#include <hip/hip_runtime.h>

typedef unsigned int uint;
typedef unsigned short ushort;
typedef __attribute__((ext_vector_type(8))) short bf16x8;
typedef __attribute__((ext_vector_type(4))) float f32x4;

namespace {
constexpr int kS = 2048;
constexpr int kD = 512;
constexpr int kH = 8;
constexpr int kBand = 16;
}  // namespace

static __device__ __forceinline__ ushort f2bf(float f) {
  uint u = __builtin_bit_cast(uint, f);
  u = (u + 0x7fffu + ((u >> 16) & 1u)) >> 16;  // RNE
  return (ushort)u;
}

// 8 fp32 -> bf16x8 via v_cvt_pk_bf16_f32 (RNE; bit-identical to f2bf).
static __device__ __forceinline__ bf16x8 cvt8(f32x4 lo, f32x4 hi) {
  uint4 r;
  asm("v_cvt_pk_bf16_f32 %0, %1, %2" : "=v"(r.x) : "v"(lo[0]), "v"(lo[1]));
  asm("v_cvt_pk_bf16_f32 %0, %1, %2" : "=v"(r.y) : "v"(lo[2]), "v"(lo[3]));
  asm("v_cvt_pk_bf16_f32 %0, %1, %2" : "=v"(r.z) : "v"(hi[0]), "v"(hi[1]));
  asm("v_cvt_pk_bf16_f32 %0, %1, %2" : "=v"(r.w) : "v"(hi[2]), "v"(hi[3]));
  return __builtin_bit_cast(bf16x8, r);
}

// global -> LDS direct DMA, 16B/lane. LDS dest = wave-uniform base + lane*16.
#define GLD16(gp, lp)                                                   \
  __builtin_amdgcn_global_load_lds(                                     \
      (const __attribute__((address_space(1))) uint*)(gp),              \
      (__attribute__((address_space(3))) uint*)(lp), 16, 0, 0)

// Compiler-level memory fence (no instruction): pins vmem issue order so
// vmcnt FIFO-retirement arguments stay valid under scheduling.
#define FENCE asm volatile("" ::: "memory")

// ---------------------------------------------------------------------------
// Prep: weight transpose only. 256 blocks: WT[z][n][k] = bf16(W[z][k][n]).
// ---------------------------------------------------------------------------
__global__ __launch_bounds__(256) void prep_kernel(
    const float* __restrict__ wq, const float* __restrict__ wk,
    const float* __restrict__ wv, const float* __restrict__ wo,
    ushort* __restrict__ WT) {
  __shared__ float Ws[64][65];
  const int w = blockIdx.x;  // 0..255
  const int tid = threadIdx.x;
  const int z = w >> 6;
  const float* W = z == 0 ? wq : (z == 1 ? wk : (z == 2 ? wv : wo));
  ushort* T = WT + (size_t)z * kD * kD;
  const int kt = ((w >> 3) & 7) * 64, nt = (w & 7) * 64;
  const int r = tid >> 2, c0 = (tid & 3) * 16;
#pragma unroll
  for (int i = 0; i < 4; ++i) {
    const float4 x =
        *(const float4*)(W + (size_t)(kt + r) * kD + nt + c0 + i * 4);
    Ws[r][c0 + i * 4 + 0] = x.x;
    Ws[r][c0 + i * 4 + 1] = x.y;
    Ws[r][c0 + i * 4 + 2] = x.z;
    Ws[r][c0 + i * 4 + 3] = x.w;
  }
  __syncthreads();
  const int n = tid >> 2, k0 = (tid & 3) * 16;
  alignas(16) ushort tmp[16];
#pragma unroll
  for (int i = 0; i < 16; ++i) tmp[i] = f2bf(Ws[k0 + i][n]);
  ushort* dst = T + (size_t)(nt + n) * kD + kt + k0;
  *(uint4*)(dst + 0) = *(const uint4*)&tmp[0];
  *(uint4*)(dst + 8) = *(const uint4*)&tmp[8];
}

// ---------------------------------------------------------------------------
// QKV GEMM: 128x128, BK=32, fp32 A read ONCE from HBM, reg-staged to bf16 LDS
// (global->VGPR->cvt_pk->ds_write_b128). B via global_load_lds, 3-stage.
// LDS = 48 KB -> 3 blocks/CU; grid 768 = fully co-resident (no tail).
// Sync: compiler's vmcnt wait before cvt(A(t+1)) retires the older B(t) DMA
// (FIFO), so per-iter we only need lgkmcnt(0)+s_barrier. FENCE pins order.
// mode = blockIdx.z: 0: q@WTq+bq -> Qp; 1: k@WTk+bk -> Kp;
//                    2: v@WTv+bv -> VT (transposed [bh*64+d][2048]).
// ---------------------------------------------------------------------------
__global__ __launch_bounds__(256, 3) void gemm_qkv(
    const float* __restrict__ q, const float* __restrict__ k,
    const float* __restrict__ v, const ushort* __restrict__ WT,
    const float* __restrict__ bq, const float* __restrict__ bk,
    const float* __restrict__ bv, ushort* __restrict__ Qp,
    ushort* __restrict__ Kp, ushort* __restrict__ VT) {
  const int mode = blockIdx.z;
  const float* Ab = mode == 0 ? q : (mode == 1 ? k : v);
  const float* bias = mode == 0 ? bq : (mode == 1 ? bk : bv);
  const ushort* BT = WT + (size_t)mode * kD * kD;

  constexpr int A_STAGE = 128 * 32;    // 4096 ushorts (bf16 stage)
  constexpr int B_BASE = 3 * A_STAGE;  // 12288
  __shared__ alignas(16) ushort smem[B_BASE + 12288];  // 48 KB

  const int tid = threadIdx.x;
  const int wave = tid >> 6, lane = tid & 63, l15 = lane & 15, qd = lane >> 4;
  const int wm = (wave >> 1) * 64, wn = (wave & 1) * 64;
  // XCD-aware swizzle: x%8 = XCD; a row-block's 4 col-blocks share an XCD.
  const int lin = blockIdx.x;
  const int xcd = lin & 7, j = lin >> 3;
  const int rblk = xcd + 8 * (j >> 2), cblk = j & 3;
  const int row0 = rblk * 128, col0 = cblk * 128;
  const int sw = (l15 & 3) ^ (l15 >> 2);

  // A reg-staging: 2 threads/row, 16 fp32 each -> 2 swizzled bf16x8 chunks.
  // LDS chunk c of row r sits at position c ^ s(r), s(r)=(r&3)^((r>>2)&3).
  const int ar = tid >> 1;        // row 0..127
  const int acp = (tid & 1) * 2;  // chunk pair {acp, acp+1}
  const int as_ = (ar & 3) ^ ((ar >> 2) & 3);
  const float* pAg = Ab + (size_t)(row0 + ar) * kD + acp * 8;
  const uint wA0 = (uint)(ar * 32 + ((acp ^ as_) * 8));
  const uint wA1 = (uint)(ar * 32 + (((acp + 1) ^ as_) * 8));

  const ushort* pB[2];
  uint ldsB[2];
#pragma unroll
  for (int i = 0; i < 2; ++i) {
    const int linear = i * 256 + tid;
    const int r = linear >> 2, c = linear & 3;
    const int g = c ^ ((r & 3) ^ ((r >> 2) & 3));
    pB[i] = BT + (size_t)(col0 + r) * kD + g * 8;
    ldsB[i] = (uint)B_BASE + (uint)(i * 256 + wave * 64) * 8;
  }

  f32x4 areg[2][4];
#define LOADA(slot, kk)                                               \
  { _Pragma("unroll") for (int c = 0; c < 4; ++c)                     \
      areg[slot][c] = *(const f32x4*)(pAg + (kk) + c * 4); }
#define WRITEA(st, slot)                                              \
  {                                                                   \
    *(bf16x8*)&smem[(st) * A_STAGE + wA0] =                           \
        cvt8(areg[slot][0], areg[slot][1]);                           \
    *(bf16x8*)&smem[(st) * A_STAGE + wA1] =                           \
        cvt8(areg[slot][2], areg[slot][3]);                           \
  }
#define ISSUEB(kk, st)                                                \
  { _Pragma("unroll") for (int i = 0; i < 2; ++i)                     \
      GLD16(pB[i] + (kk), &smem[ldsB[i] + (st) * 4096]); }

  f32x4 acc[4][4];
#pragma unroll
  for (int mi = 0; mi < 4; ++mi)
#pragma unroll
    for (int ni = 0; ni < 4; ++ni) acc[mi][ni] = (f32x4)(0.f);

  // Prologue. Issue order matters: [A0, B0, A1, B1] so cvt(A1) retires B0.
  LOADA(0, 0);
  FENCE;
  ISSUEB(0, 0);
  FENCE;
  LOADA(1, 32);
  FENCE;
  ISSUEB(32, 1);
  FENCE;
  WRITEA(0, 0);  // compiler inserts vmcnt wait for A0 here

#pragma unroll
  for (int it = 0; it < 16; ++it) {
    if (it < 15) {
      WRITEA((it + 1) % 3, (it + 1) & 1);  // vmcnt wait -> retires B(it) too
      if (it < 14) LOADA(it & 1, (it + 2) * 32);
      asm volatile("s_waitcnt lgkmcnt(0)\n\ts_barrier" ::: "memory");
      if (it < 14) ISSUEB((it + 2) * 32, (it + 2) % 3);
      FENCE;
    } else {
      asm volatile("s_waitcnt vmcnt(0) lgkmcnt(0)\n\ts_barrier" ::: "memory");
    }
    const ushort* as2 = &smem[(it % 3) * A_STAGE];
    const ushort* bs = &smem[B_BASE + (it % 3) * 4096];
    bf16x8 af[4], br[4];
#pragma unroll
    for (int mi = 0; mi < 4; ++mi)
      af[mi] = *(const bf16x8*)&as2[(wm + mi * 16 + l15) * 32 + (qd ^ sw) * 8];
#pragma unroll
    for (int ni = 0; ni < 4; ++ni)
      br[ni] = *(const bf16x8*)&bs[(wn + ni * 16 + l15) * 32 + (qd ^ sw) * 8];
#pragma unroll
    for (int mi = 0; mi < 4; ++mi)
#pragma unroll
      for (int ni = 0; ni < 4; ++ni)
        acc[mi][ni] = __builtin_amdgcn_mfma_f32_16x16x32_bf16(
            af[mi], br[ni], acc[mi][ni], 0, 0, 0);
  }
#undef LOADA
#undef WRITEA
#undef ISSUEB

  float bcol[4];
#pragma unroll
  for (int ni = 0; ni < 4; ++ni) bcol[ni] = bias[col0 + wn + ni * 16 + l15];

  __syncthreads();  // safe to reuse smem for the epilogue transpose

  // bf16 outputs: per-wave 64x64 transpose through LDS (stride 72 ushorts),
  // then 8 x dwordx4 global stores per lane.
  ushort* T = &smem[wave * 4608];
  if (mode <= 1) {  // place [token_local][d_local]
#pragma unroll
    for (int mi = 0; mi < 4; ++mi)
#pragma unroll
      for (int ni = 0; ni < 4; ++ni)
#pragma unroll
        for (int r = 0; r < 4; ++r)
          T[(mi * 16 + qd * 4 + r) * 72 + ni * 16 + l15] =
              f2bf(acc[mi][ni][r] + bcol[ni]);
  } else {  // mode 2: place [d_local][token_local]
#pragma unroll
    for (int mi = 0; mi < 4; ++mi)
#pragma unroll
      for (int ni = 0; ni < 4; ++ni)
#pragma unroll
        for (int r = 0; r < 4; ++r)
          T[(ni * 16 + l15) * 72 + mi * 16 + qd * 4 + r] =
              f2bf(acc[mi][ni][r] + bcol[ni]);
  }
  asm volatile("s_waitcnt lgkmcnt(0)" ::: "memory");  // wave-local visibility

  const ushort* Trow = &smem[wave * 4608 + lane * 72];
  if (mode <= 1) {
    ushort* C = (mode == 0) ? Qp : Kp;
    ushort* dst = C + (size_t)(row0 + wm + lane) * kD + col0 + wn;
#pragma unroll
    for (int c = 0; c < 8; ++c)
      *(uint4*)(dst + c * 8) = *(const uint4*)(Trow + c * 8);
  } else {
    const int n_g = col0 + wn + lane;
    const int h = n_g >> 6, d = n_g & 63;
    const int t0 = row0 + wm;
    const int b = t0 >> 11, ss = t0 & (kS - 1);
    ushort* dst = VT + ((size_t)(b * kH + h) * 64 + d) * kS + ss;
#pragma unroll
    for (int c = 0; c < 8; ++c)
      *(uint4*)(dst + c * 8) = *(const uint4*)(Trow + c * 8);
  }
}

// ---------------------------------------------------------------------------
// MFMA banded attention, 32-query tiles. One wave per tile per (b,h).
// grid (64,32) = 2048 waves = 2 waves/SIMD machine-wide (was 1 with 64-tiles).
// K window per tile: [q0-16, q0+48) = 64 keys (was 96 for 64-tiles).
// ---------------------------------------------------------------------------
__global__ __launch_bounds__(64, 2) void attn_kernel(
    const ushort* __restrict__ Qp, const ushort* __restrict__ Kp,
    const ushort* __restrict__ VT, ushort* __restrict__ Ob) {
  __shared__ alignas(16) ushort Pl[32 * 72];  // P scatter; reused for O xpose

  const int lane = threadIdx.x, l15 = lane & 15, qd = lane >> 4;
  const int bh = blockIdx.y, b = bh >> 3, h = bh & 7;
  const int q0 = blockIdx.x * 32;
  const int colA = h * 64;

  bf16x8 qf[2][2], kf[4][2];
#pragma unroll
  for (int mi = 0; mi < 2; ++mi) {
    const size_t base =
        ((size_t)b * kS + q0 + mi * 16 + l15) * kD + colA + qd * 8;
#pragma unroll
    for (int kc = 0; kc < 2; ++kc)
      qf[mi][kc] = *(const bf16x8*)&Qp[base + kc * 32];
  }
#pragma unroll
  for (int ni = 0; ni < 4; ++ni) {
    int key = q0 - kBand + ni * 16 + l15;
    key = key < 0 ? 0 : (key > kS - 1 ? kS - 1 : key);  // clamp; masked below
    const size_t base = ((size_t)b * kS + key) * kD + colA + qd * 8;
#pragma unroll
    for (int kc = 0; kc < 2; ++kc)
      kf[ni][kc] = *(const bf16x8*)&Kp[base + kc * 32];
  }

  f32x4 S[2][4];
#pragma unroll
  for (int mi = 0; mi < 2; ++mi)
#pragma unroll
    for (int ni = 0; ni < 4; ++ni) S[mi][ni] = (f32x4)(0.f);
#pragma unroll
  for (int mi = 0; mi < 2; ++mi)
#pragma unroll
    for (int ni = 0; ni < 4; ++ni)
#pragma unroll
      for (int kc = 0; kc < 2; ++kc)
        S[mi][ni] = __builtin_amdgcn_mfma_f32_16x16x32_bf16(
            qf[mi][kc], kf[ni][kc], S[mi][ni], 0, 0, 0);

#pragma unroll
  for (int mi = 0; mi < 2; ++mi)
#pragma unroll
    for (int ni = 0; ni < 4; ++ni)
#pragma unroll
      for (int r = 0; r < 4; ++r) {
        const int q_local = mi * 16 + qd * 4 + r;
        const int key_local = ni * 16 + l15;
        const int key = q0 - kBand + key_local;
        const int dlt = key_local - q_local;
        const bool ok = (dlt >= 0) && (dlt <= 32) && (key >= 0) && (key < kS);
        S[mi][ni][r] = ok ? S[mi][ni][r] * 0.125f : -3.0e38f;
      }

  float inv[2][4];
#pragma unroll
  for (int mi = 0; mi < 2; ++mi)
#pragma unroll
    for (int r = 0; r < 4; ++r) {
      float m = S[mi][0][r];
#pragma unroll
      for (int ni = 1; ni < 4; ++ni) m = fmaxf(m, S[mi][ni][r]);
      m = fmaxf(m, __shfl_xor(m, 1));
      m = fmaxf(m, __shfl_xor(m, 2));
      m = fmaxf(m, __shfl_xor(m, 4));
      m = fmaxf(m, __shfl_xor(m, 8));
      float s = 0.f;
#pragma unroll
      for (int ni = 0; ni < 4; ++ni) {
        const float e = __expf(S[mi][ni][r] - m);
        S[mi][ni][r] = e;
        s += e;
      }
      s += __shfl_xor(s, 1);
      s += __shfl_xor(s, 2);
      s += __shfl_xor(s, 4);
      s += __shfl_xor(s, 8);
      inv[mi][r] = 1.f / s;
    }

  // P -> LDS (C-layout scatter, stride 72), read back in A-layout
#pragma unroll
  for (int mi = 0; mi < 2; ++mi)
#pragma unroll
    for (int ni = 0; ni < 4; ++ni)
#pragma unroll
      for (int r = 0; r < 4; ++r)
        Pl[(mi * 16 + qd * 4 + r) * 72 + ni * 16 + l15] = f2bf(S[mi][ni][r]);
  __syncthreads();

  f32x4 O[2][4];
#pragma unroll
  for (int mi = 0; mi < 2; ++mi)
#pragma unroll
    for (int nt = 0; nt < 4; ++nt) O[mi][nt] = (f32x4)(0.f);

#pragma unroll
  for (int kc = 0; kc < 2; ++kc) {
    bf16x8 pf[2], vfr[4];
#pragma unroll
    for (int mi = 0; mi < 2; ++mi)
      pf[mi] = *(const bf16x8*)&Pl[(mi * 16 + l15) * 72 + kc * 32 + qd * 8];
    int kb0 = q0 - kBand + kc * 32 + qd * 8;
    kb0 = kb0 < 0 ? 0 : (kb0 > kS - 8 ? kS - 8 : kb0);  // clamp; P=0 there
#pragma unroll
    for (int nt = 0; nt < 4; ++nt)
      vfr[nt] =
          *(const bf16x8*)&VT[((size_t)bh * 64 + nt * 16 + l15) * kS + kb0];
#pragma unroll
    for (int mi = 0; mi < 2; ++mi)
#pragma unroll
      for (int nt = 0; nt < 4; ++nt)
        O[mi][nt] = __builtin_amdgcn_mfma_f32_16x16x32_bf16(pf[mi], vfr[nt],
                                                            O[mi][nt], 0, 0, 0);
  }

  // O transpose through LDS (reuse Pl; same-wave DS ops are in-order)
#pragma unroll
  for (int mi = 0; mi < 2; ++mi)
#pragma unroll
    for (int nt = 0; nt < 4; ++nt)
#pragma unroll
      for (int r = 0; r < 4; ++r)
        Pl[(mi * 16 + qd * 4 + r) * 72 + nt * 16 + l15] =
            f2bf(O[mi][nt][r] * inv[mi][r]);
  asm volatile("s_waitcnt lgkmcnt(0)" ::: "memory");

  // 32 rows x 64 cols: 2 lanes per row, 64B each.
  const int row = lane >> 1, half = lane & 1;
  ushort* dst = Ob + ((size_t)b * kS + q0 + row) * kD + colA + half * 32;
  const ushort* Trow = &Pl[row * 72 + half * 32];
#pragma unroll
  for (int c = 0; c < 4; ++c)
    *(uint4*)(dst + c * 8) = *(const uint4*)(Trow + c * 8);
}

// ---------------------------------------------------------------------------
// Out-projection GEMM: 64x128 tiles, bf16 A (Ob) via global_load_lds,
// 3-stage, fp32 direct stores. 512 blocks, 36 KB LDS -> 4 blocks/CU.
// ---------------------------------------------------------------------------
__global__ __launch_bounds__(256) void gemm_out(
    const ushort* __restrict__ Ab, const ushort* __restrict__ BT,
    const float* __restrict__ bias, float* __restrict__ outp) {
  constexpr int A_STAGE = 64 * 32;     // 2048 ushorts
  constexpr int B_BASE = 3 * A_STAGE;  // 6144
  __shared__ alignas(16) ushort smem[B_BASE + 12288];  // 36 KB

  const int tid = threadIdx.x;
  const int wave = tid >> 6, lane = tid & 63, l15 = lane & 15, qd = lane >> 4;
  const int wn = wave * 32;
  const int lin = blockIdx.x;
  const int xcd = lin & 7, j = lin >> 3;
  const int rblk = xcd + 8 * (j >> 2), cblk = j & 3;
  const int row0 = rblk * 64, col0 = cblk * 128;
  const int sw = (l15 & 3) ^ (l15 >> 2);

  const ushort* pA0;
  uint ldsA0;
  {
    const int r = tid >> 2, c = tid & 3;
    const int g = c ^ ((r & 3) ^ ((r >> 2) & 3));
    pA0 = Ab + (size_t)(row0 + r) * kD + g * 8;
    ldsA0 = (uint)(wave * 64) * 8;
  }
  const ushort* pB[2];
  uint ldsB[2];
#pragma unroll
  for (int i = 0; i < 2; ++i) {
    const int linear = i * 256 + tid;
    const int r = linear >> 2, c = linear & 3;
    const int g = c ^ ((r & 3) ^ ((r >> 2) & 3));
    pB[i] = BT + (size_t)(col0 + r) * kD + g * 8;
    ldsB[i] = (uint)B_BASE + (uint)(i * 256 + wave * 64) * 8;
  }

#define ISSUE3(kk, st)                                                \
  {                                                                   \
    GLD16(pA0 + (kk), &smem[ldsA0 + (st) * A_STAGE]);                 \
    _Pragma("unroll") for (int i = 0; i < 2; ++i)                     \
        GLD16(pB[i] + (kk), &smem[ldsB[i] + (st) * 4096]);            \
  }

  f32x4 acc[4][2];
#pragma unroll
  for (int mi = 0; mi < 4; ++mi)
#pragma unroll
    for (int ni = 0; ni < 2; ++ni) acc[mi][ni] = (f32x4)(0.f);

  ISSUE3(0, 0);
  ISSUE3(32, 1);
#pragma unroll
  for (int it = 0; it < 16; ++it) {
    if (it < 15)
      asm volatile("s_waitcnt vmcnt(3) lgkmcnt(0)\n\ts_barrier" ::: "memory");
    else
      asm volatile("s_waitcnt vmcnt(0) lgkmcnt(0)\n\ts_barrier" ::: "memory");
    if (it < 14) ISSUE3((it + 2) * 32, (it + 2) % 3);
    const ushort* as2 = &smem[(it % 3) * A_STAGE];
    const ushort* bs = &smem[B_BASE + (it % 3) * 4096];
    bf16x8 af[4], br[2];
#pragma unroll
    for (int mi = 0; mi < 4; ++mi)
      af[mi] = *(const bf16x8*)&as2[(mi * 16 + l15) * 32 + (qd ^ sw) * 8];
#pragma unroll
    for (int ni = 0; ni < 2; ++ni)
      br[ni] = *(const bf16x8*)&bs[(wn + ni * 16 + l15) * 32 + (qd ^ sw) * 8];
#pragma unroll
    for (int mi = 0; mi < 4; ++mi)
#pragma unroll
      for (int ni = 0; ni < 2; ++ni)
        acc[mi][ni] = __builtin_amdgcn_mfma_f32_16x16x32_bf16(
            af[mi], br[ni], acc[mi][ni], 0, 0, 0);
  }
#undef ISSUE3

#pragma unroll
  for (int ni = 0; ni < 2; ++ni) {
    const int n_g = col0 + wn + ni * 16 + l15;
    const float bc = bias[n_g];
#pragma unroll
    for (int mi = 0; mi < 4; ++mi)
#pragma unroll
      for (int r = 0; r < 4; ++r) {
        const int token = row0 + mi * 16 + qd * 4 + r;
        outp[(size_t)token * kD + n_g] = acc[mi][ni][r] + bc;
      }
  }
}

extern "C" void kernel_launch(void* const* d_in, const int* in_sizes, int n_in,
                              void* d_out, int out_size, void* d_ws,
                              size_t ws_size, hipStream_t stream) {
  const float* q = (const float*)d_in[0];
  const float* k = (const float*)d_in[1];
  const float* v = (const float*)d_in[2];
  const float* wq = (const float*)d_in[3];
  const float* bq = (const float*)d_in[4];
  const float* wk = (const float*)d_in[5];
  const float* bk = (const float*)d_in[6];
  const float* wv = (const float*)d_in[7];
  const float* bv = (const float*)d_in[8];
  const float* wo = (const float*)d_in[9];
  const float* bo = (const float*)d_in[10];
  float* out = (float*)d_out;

  // ws (~34 MB), no aliasing.
  const size_t n1 = (size_t)8192 * kD;  // 4M ushorts = 8 MB
  ushort* Qp = (ushort*)d_ws;
  ushort* Kp = Qp + n1;
  ushort* VT = Kp + n1;
  ushort* Ob = VT + n1;
  ushort* WT = Ob + n1;

  prep_kernel<<<dim3(256), 256, 0, stream>>>(wq, wk, wv, wo, WT);
  gemm_qkv<<<dim3(256, 1, 3), 256, 0, stream>>>(q, k, v, WT, bq, bk, bv, Qp,
                                                Kp, VT);
  attn_kernel<<<dim3(kS / 32, 32), 64, 0, stream>>>(Qp, Kp, VT, Ob);
  gemm_out<<<dim3(512), 256, 0, stream>>>(Ob, WT + (size_t)3 * kD * kD, bo,
                                          out);
}